// Round 1
// baseline (1300.786 us; speedup 1.0000x reference)
//
#include <hip/hip_runtime.h>
#include <math.h>

constexpr int L = 8192;
constexpr int B = 4;
constexpr int D = 512;
constexpr int NDIM = 16;
constexpr int Z = 128;
constexpr int W = 128;
constexpr float NEGF = -50000.0f;
constexpr int CL = 256;    // conv scan emit chunk
constexpr int WARM = 256;  // warmup steps; q^256 < 1e-19 (q <= 0.839)

// ---------------- 1. per-(d,n) decay q and coefficient c (fp64) ----------------
__global__ __launch_bounds__(256) void k_prep(const float* __restrict__ delta,
                                              const float* __restrict__ alpha,
                                              const float* __restrict__ beta,
                                              const float* __restrict__ gamma,
                                              double* __restrict__ qdn,
                                              double* __restrict__ cdn) {
  int i = blockIdx.x * 256 + threadIdx.x;
  if (i >= D * NDIM) return;
  double p = 1.0 / (1.0 + exp(-(double)delta[i]));
  double a = 1.0 / (1.0 + exp(-(double)alpha[i]));
  qdn[i] = 1.0 - p * a;                                    // exp(log1p(-p*a))
  cdn[i] = p * (double)beta[i] * (double)gamma[i] * 0.25;  // scale = 1/sqrt(NDIM)
}

// ---------------- 2. conv as 16-state scan + mx = silu(conv + x*omega) ----------------
// thread = (chunk, b, d); emits CL outputs after WARM warmup steps. fp64 states.
__global__ __launch_bounds__(256) void k_conv(const float* __restrict__ x,
                                              const float* __restrict__ omega,
                                              const double* __restrict__ qdn,
                                              const double* __restrict__ cdn,
                                              float* __restrict__ mx) {
  int blk = blockIdx.x;          // (L/CL)*B*2 blocks
  int dh = blk & 1;
  int b  = (blk >> 1) & 3;
  int ch = blk >> 3;
  int d = dh * 256 + threadIdx.x;
  double q[NDIM], c[NDIM], s[NDIM];
#pragma unroll
  for (int n = 0; n < NDIM; ++n) {
    q[n] = qdn[d * NDIM + n];
    c[n] = cdn[d * NDIM + n];
    s[n] = 0.0;
  }
  double om = (double)omega[d];
  int l0 = ch * CL;
  int lw = l0 - WARM; if (lw < 0) lw = 0;
  for (int l = lw; l < l0; ++l) {
    double xv = (double)x[(size_t)(l * B + b) * D + d];
#pragma unroll
    for (int n = 0; n < NDIM; ++n) s[n] = fma(q[n], s[n], xv);
  }
  for (int l = l0; l < l0 + CL; ++l) {
    double xv = (double)x[(size_t)(l * B + b) * D + d];
    double conv = 0.0;
#pragma unroll
    for (int n = 0; n < NDIM; ++n) {
      s[n] = fma(q[n], s[n], xv);
      conv = fma(c[n], s[n], conv);
    }
    float m = (float)(conv + xv * om);
    float sg = 1.0f / (1.0f + expf(-m));
    mx[((size_t)b * L + l) * D + d] = m * sg;   // store (B,L,D)
  }
}

// ---------------- 3. logit = mx@Wp + bp (fp64), pi, sel ----------------
__global__ __launch_bounds__(256) void k_logit(const float* __restrict__ mx,
                                               const float* __restrict__ Wp,
                                               const float* __restrict__ bp,
                                               const float* __restrict__ temp,
                                               float* __restrict__ pi,
                                               int* __restrict__ selb) {
  int rid = blockIdx.x * 4 + (threadIdx.x >> 6);  // row = b*L+l
  int lane = threadIdx.x & 63;
  const float* row = mx + (size_t)rid * D;
  double acc = 0.0;
#pragma unroll
  for (int i = 0; i < D / 64; ++i)
    acc += (double)row[lane + 64 * i] * (double)Wp[lane + 64 * i];
  for (int off = 32; off; off >>= 1) acc += __shfl_down(acc, off, 64);
  if (lane == 0) {
    double logit = acc + (double)bp[0];
    double scl = logit / exp((double)temp[0]);
    pi[rid] = (float)(1.0 / (1.0 + exp(-scl)));
    selb[rid] = (logit > 0.0) ? 1 : 0;   // pi>0.5 <=> logit+bp>0
  }
}

// ---------------- 4. per-batch scan: idx (1-based, 0 if unselected), src, counts ----------------
__global__ __launch_bounds__(256) void k_scan(const int* __restrict__ selb,
                                              int* __restrict__ idx,
                                              int* __restrict__ src,
                                              int* __restrict__ counts) {
  int b = blockIdx.x;
  int t = threadIdx.x;
  __shared__ int part[256];
  const int PER = L / 256;  // 32
  int base = b * L + t * PER;
  int loc[PER];
  int cnt = 0;
#pragma unroll
  for (int i = 0; i < PER; ++i) { loc[i] = selb[base + i]; cnt += loc[i]; }
  part[t] = cnt;
  __syncthreads();
  for (int off = 1; off < 256; off <<= 1) {
    int v = (t >= off) ? part[t - off] : 0;
    __syncthreads();
    part[t] += v;
    __syncthreads();
  }
  int run = (t == 0) ? 0 : part[t - 1];
#pragma unroll
  for (int i = 0; i < PER; ++i) {
    int sflag = loc[i];
    run += sflag;
    idx[base + i] = sflag ? run : 0;
    if (sflag) src[b * L + run - 1] = t * PER + i;
  }
  if (t == 255) counts[b] = part[255];
}

// ---------------- 5. gather compacted c ----------------
__global__ __launch_bounds__(256) void k_buildc(const float* __restrict__ mx,
                                                const int* __restrict__ src,
                                                const int* __restrict__ counts,
                                                float* __restrict__ c) {
  int row = blockIdx.x;      // b*L + j
  int b = row >> 13;
  int j = row & (L - 1);
  int t = threadIdx.x;
  float v0 = 0.f, v1 = 0.f;
  if (j < counts[b]) {
    const float* mr = mx + ((size_t)b * L + src[row]) * D;
    v0 = mr[t];
    v1 = mr[t + 256];
  }
  float* cr = c + (size_t)row * D;
  cr[t] = v0;
  cr[t + 256] = v1;
}

// ---------------- 6. fp32 tiled GEMM + silu: out(32768,N) = silu(A(32768,512) @ Wm(512,N)) ----------------
__global__ __launch_bounds__(256) void k_gemm_silu(const float* __restrict__ A,
                                                   const float* __restrict__ Wm,
                                                   float* __restrict__ out, int N) {
  __shared__ float As[16][65];
  __shared__ float Bs[16][65];
  int m0 = blockIdx.x * 64, n0 = blockIdx.y * 64;
  int tid = threadIdx.x;
  int tx = tid & 15, ty = tid >> 4;
  float acc[4][4] = {};
  for (int k0 = 0; k0 < 512; k0 += 16) {
    {
      int ar = tid >> 2, ac = (tid & 3) * 4;
      const float4 av = *(const float4*)&A[(size_t)(m0 + ar) * 512 + k0 + ac];
      As[ac + 0][ar] = av.x; As[ac + 1][ar] = av.y;
      As[ac + 2][ar] = av.z; As[ac + 3][ar] = av.w;
    }
    {
      int br = tid >> 4, bc = (tid & 15) * 4;
      const float4 bv = *(const float4*)&Wm[(size_t)(k0 + br) * N + n0 + bc];
      Bs[br][bc + 0] = bv.x; Bs[br][bc + 1] = bv.y;
      Bs[br][bc + 2] = bv.z; Bs[br][bc + 3] = bv.w;
    }
    __syncthreads();
#pragma unroll
    for (int kk = 0; kk < 16; ++kk) {
      float a[4], bb[4];
#pragma unroll
      for (int i = 0; i < 4; ++i) a[i] = As[kk][ty * 4 + i];
#pragma unroll
      for (int j = 0; j < 4; ++j) bb[j] = Bs[kk][tx * 4 + j];
#pragma unroll
      for (int i = 0; i < 4; ++i)
#pragma unroll
        for (int j = 0; j < 4; ++j) acc[i][j] = fmaf(a[i], bb[j], acc[i][j]);
    }
    __syncthreads();
  }
#pragma unroll
  for (int i = 0; i < 4; ++i)
#pragma unroll
    for (int j = 0; j < 4; ++j) {
      float vv = acc[i][j];
      float sg = 1.0f / (1.0f + expf(-vv));
      out[(size_t)(m0 + ty * 4 + i) * N + n0 + tx * 4 + j] = vv * sg;
    }
}

// ---------------- 7. rotary on z*g+b (positions are compacted row index) ----------------
__global__ __launch_bounds__(256) void k_rot(const float* __restrict__ z,
                                             const float* __restrict__ qg,
                                             const float* __restrict__ qb,
                                             const float* __restrict__ kg,
                                             const float* __restrict__ kb,
                                             float* __restrict__ qo,
                                             float* __restrict__ ko) {
  int tid = blockIdx.x * 256 + threadIdx.x;  // row*64 + pair
  int i = tid & 63;
  int row = tid >> 6;
  int j = row & (L - 1);
  double freq = exp(((double)(-2 * i) / 128.0) * log(10000.0));
  float angf = (float)j * (float)freq;   // mimic the reference's f32 angle rounding
  double sa, ca;
  sincos((double)angf, &sa, &ca);
  float cc = (float)ca, ss = (float)sa;
  size_t base = (size_t)row * Z + 2 * i;
  float z1 = z[base], z2 = z[base + 1];
  float q1 = z1 * qg[2 * i] + qb[2 * i], q2 = z2 * qg[2 * i + 1] + qb[2 * i + 1];
  float k1 = z1 * kg[2 * i] + kb[2 * i], k2 = z2 * kg[2 * i + 1] + kb[2 * i + 1];
  qo[base]     = q1 * cc - q2 * ss;
  qo[base + 1] = q1 * ss + q2 * cc;
  ko[base]     = k1 * cc - k2 * ss;
  ko[base + 1] = k1 * ss + k2 * cc;
}

// ---------------- 8. windowed attention: 32-query chunk per block ----------------
__global__ __launch_bounds__(256) void k_attn(const float* __restrict__ q,
                                              const float* __restrict__ k,
                                              const float* __restrict__ v,
                                              const float* __restrict__ relb,
                                              const int* __restrict__ counts,
                                              float* __restrict__ h) {
  __shared__ float qs[32][Z + 1];
  __shared__ float ks[16][Z + 1];
  __shared__ float sc[32][2 * W + 1];
  int blk = blockIdx.x;
  int qc = blk & 3;
  int n  = (blk >> 2) & 63;
  int b  = blk >> 8;
  int cnt = counts[b];
  int tid = threadIdx.x;
  int q0 = n * W + qc * 32;
  int kbase = n * W - W;
  // stage queries
  for (int u = tid; u < 32 * Z; u += 256) {
    int r = u >> 7, cix = u & 127;
    qs[r][cix] = q[((size_t)b * L + q0 + r) * Z + cix];
  }
  __syncthreads();
  // 16 key chunks of 16 rows
  for (int kc = 0; kc < 16; ++kc) {
    for (int u = tid; u < 16 * Z; u += 256) {
      int r = u >> 7, cix = u & 127;
      int jk = kbase + kc * 16 + r;
      int jcl = jk < 0 ? 0 : jk;
      ks[r][cix] = k[((size_t)b * L + jcl) * Z + cix];
    }
    __syncthreads();
    int qi = tid & 31;
    int kio = tid >> 5;  // 0..7
#pragma unroll
    for (int u = 0; u < 2; ++u) {
      int ki = kio + 8 * u;
      float acc = 0.f;
#pragma unroll
      for (int zz = 0; zz < Z; ++zz) acc = fmaf(qs[qi][zz], ks[ki][zz], acc);
      int kcol = kc * 16 + ki;
      int kabs = kbase + kcol;
      int ww = qc * 32 + qi;        // query index within window
      int qabs = q0 + qi;
      bool valid = (kabs >= 0) && (kabs <= qabs) && (kabs < cnt);
      float bias = relb[kcol + 127 - ww];
      sc[qi][kcol] = valid ? (acc * 0.088388347648318447f + bias) : NEGF;
    }
    __syncthreads();
  }
  // softmax over 256 keys; wave handles 8 rows
  int wave = tid >> 6, lane = tid & 63;
#pragma unroll
  for (int r8 = 0; r8 < 8; ++r8) {
    int qi = wave * 8 + r8;
    float mxv = -1e30f;
#pragma unroll
    for (int uu = 0; uu < 4; ++uu) mxv = fmaxf(mxv, sc[qi][lane + 64 * uu]);
    for (int off = 32; off; off >>= 1) mxv = fmaxf(mxv, __shfl_xor(mxv, off, 64));
    float ev[4], sum = 0.f;
#pragma unroll
    for (int uu = 0; uu < 4; ++uu) {
      ev[uu] = __expf(sc[qi][lane + 64 * uu] - mxv);
      sum += ev[uu];
    }
    for (int off = 32; off; off >>= 1) sum += __shfl_xor(sum, off, 64);
    float inv = 1.0f / sum;
#pragma unroll
    for (int uu = 0; uu < 4; ++uu) sc[qi][lane + 64 * uu] = ev[uu] * inv;
  }
  __syncthreads();
  // PV: wave -> 8 query rows, lanes -> 64 d-slots x 8 iters
  float acc[8][8] = {};
  for (int kk = 0; kk < 2 * W; ++kk) {
    int jk = kbase + kk;
    if (jk < 0) continue;   // masked (weight 0) and would be OOB for b==0
    const float* vr = v + ((size_t)b * L + jk) * D;
    float vv[8];
#pragma unroll
    for (int i2 = 0; i2 < 8; ++i2) vv[i2] = vr[lane + 64 * i2];
#pragma unroll
    for (int r8 = 0; r8 < 8; ++r8) {
      float a = sc[wave * 8 + r8][kk];
#pragma unroll
      for (int i2 = 0; i2 < 8; ++i2) acc[r8][i2] = fmaf(a, vv[i2], acc[r8][i2]);
    }
  }
#pragma unroll
  for (int r8 = 0; r8 < 8; ++r8) {
    float* hr = h + ((size_t)b * L + q0 + wave * 8 + r8) * D;
#pragma unroll
    for (int i2 = 0; i2 < 8; ++i2) hr[lane + 64 * i2] = acc[r8][i2];
  }
}

// ---------------- 9. out = x + gather(h, idx) * pi ----------------
__global__ __launch_bounds__(256) void k_final(const float* __restrict__ x,
                                               const float* __restrict__ h,
                                               const float* __restrict__ pi,
                                               const int* __restrict__ idx,
                                               float* __restrict__ out) {
  size_t tid = (size_t)blockIdx.x * 256 + threadIdx.x;  // (l*B+b)*D+d
  int d = tid & (D - 1);
  size_t rem = tid >> 9;
  int b = (int)(rem & 3);
  int l = (int)(rem >> 2);
  int ix = idx[b * L + l];
  float val = x[tid];
  if (ix > 0) val += h[((size_t)b * L + ix - 1) * D + d] * pi[b * L + l];
  out[tid] = val;
}

extern "C" void kernel_launch(void* const* d_in, const int* in_sizes, int n_in,
                              void* d_out, int out_size, void* d_ws, size_t ws_size,
                              hipStream_t stream) {
  const float* x     = (const float*)d_in[0];
  const float* delta = (const float*)d_in[1];
  const float* alpha = (const float*)d_in[2];
  const float* beta  = (const float*)d_in[3];
  const float* gamma = (const float*)d_in[4];
  const float* omega = (const float*)d_in[5];
  const float* Wp    = (const float*)d_in[6];
  const float* bp    = (const float*)d_in[7];
  const float* temp  = (const float*)d_in[8];
  const float* Wz    = (const float*)d_in[9];
  const float* qg    = (const float*)d_in[10];
  const float* qb    = (const float*)d_in[11];
  const float* kg    = (const float*)d_in[12];
  const float* kb    = (const float*)d_in[13];
  const float* Wv    = (const float*)d_in[14];
  const float* relb  = (const float*)d_in[15];
  (void)in_sizes; (void)n_in; (void)out_size; (void)ws_size;

  char* wsb = (char*)d_ws;
  size_t o = 0;
  auto alloc = [&](size_t bytes) {
    char* p = wsb + o;
    o += (bytes + 255) & ~(size_t)255;
    return p;
  };
  float* mxv = (float*)alloc((size_t)B * L * D * 4);  // mx, later reused for v
  float* chb = (float*)alloc((size_t)B * L * D * 4);  // c, later reused for h
  float* zb  = (float*)alloc((size_t)B * L * Z * 4);
  float* qo  = (float*)alloc((size_t)B * L * Z * 4);
  float* ko  = (float*)alloc((size_t)B * L * Z * 4);
  float* pib = (float*)alloc((size_t)B * L * 4);
  int* selb  = (int*)alloc((size_t)B * L * 4);
  int* idx   = (int*)alloc((size_t)B * L * 4);
  int* src   = (int*)alloc((size_t)B * L * 4);
  int* cnt   = (int*)alloc(256);
  double* qdn = (double*)alloc((size_t)D * NDIM * 8);
  double* cdn = (double*)alloc((size_t)D * NDIM * 8);
  // total ws use: ~178 MB

  k_prep<<<(D * NDIM + 255) / 256, 256, 0, stream>>>(delta, alpha, beta, gamma, qdn, cdn);
  k_conv<<<(L / CL) * B * 2, 256, 0, stream>>>(x, omega, qdn, cdn, mxv);
  k_logit<<<B * L / 4, 256, 0, stream>>>(mxv, Wp, bp, temp, pib, selb);
  k_scan<<<B, 256, 0, stream>>>(selb, idx, src, cnt);
  k_buildc<<<B * L, 256, 0, stream>>>(mxv, src, cnt, chb);
  k_gemm_silu<<<dim3(B * L / 64, Z / 64), 256, 0, stream>>>(chb, Wz, zb, Z);
  k_gemm_silu<<<dim3(B * L / 64, D / 64), 256, 0, stream>>>(chb, Wv, mxv, D);
  k_rot<<<B * L * (Z / 2) / 256, 256, 0, stream>>>(zb, qg, qb, kg, kb, qo, ko);
  k_attn<<<B * (L / W) * 4, 256, 0, stream>>>(qo, ko, mxv, relb, cnt, chb);
  k_final<<<(int)((size_t)L * B * D / 256), 256, 0, stream>>>(x, chb, pib, idx, (float*)d_out);
}

// Round 2
// 351.508 us; speedup vs baseline: 3.7006x; 3.7006x over previous
//
#include <hip/hip_runtime.h>
#include <math.h>

constexpr int L = 8192;
constexpr int B = 4;
constexpr int D = 512;
constexpr int NDIM = 16;
constexpr int Z = 128;
constexpr float NEGF = -50000.0f;
constexpr int CL = 128;    // conv scan emit chunk
constexpr int WARM = 256;  // q^256 < 1e-19

typedef short s16x8 __attribute__((ext_vector_type(8)));
typedef float f32x4 __attribute__((ext_vector_type(4)));

typedef __attribute__((address_space(1))) const void* as1cv;
typedef __attribute__((address_space(3))) void* as3v;

__device__ __forceinline__ void gld16(const void* g, void* l) {
  __builtin_amdgcn_global_load_lds((as1cv)g, (as3v)l, 16, 0, 0);
}

__device__ __forceinline__ unsigned short f2bf(float f) {
  unsigned u = __builtin_bit_cast(unsigned, f);
  u += 0x7fffu + ((u >> 16) & 1u);
  return (unsigned short)(u >> 16);
}

// ---------------- 1. per-(d,n) decay q and coefficient c (fp64) ----------------
__global__ __launch_bounds__(256) void k_prep(const float* __restrict__ delta,
                                              const float* __restrict__ alpha,
                                              const float* __restrict__ beta,
                                              const float* __restrict__ gamma,
                                              double* __restrict__ qdn,
                                              double* __restrict__ cdn) {
  int i = blockIdx.x * 256 + threadIdx.x;
  if (i >= D * NDIM) return;
  double p = 1.0 / (1.0 + exp(-(double)delta[i]));
  double a = 1.0 / (1.0 + exp(-(double)alpha[i]));
  qdn[i] = 1.0 - p * a;
  cdn[i] = p * (double)beta[i] * (double)gamma[i] * 0.25;  // scale = 1/sqrt(NDIM)
}

// ---------------- 2. conv as 16-state scan + mx = silu(conv + x*omega) ----------------
__global__ __launch_bounds__(256) void k_conv(const float* __restrict__ x,
                                              const float* __restrict__ omega,
                                              const double* __restrict__ qdn,
                                              const double* __restrict__ cdn,
                                              float* __restrict__ mx) {
  int blk = blockIdx.x;          // (L/CL)*B*2 blocks
  int dh = blk & 1;
  int b  = (blk >> 1) & 3;
  int ch = blk >> 3;
  int d = dh * 256 + threadIdx.x;
  double q[NDIM], c[NDIM], s[NDIM];
#pragma unroll
  for (int n = 0; n < NDIM; ++n) {
    q[n] = qdn[d * NDIM + n];
    c[n] = cdn[d * NDIM + n];
    s[n] = 0.0;
  }
  double om = (double)omega[d];
  int l0 = ch * CL;
  int lw = l0 - WARM; if (lw < 0) lw = 0;
  for (int l = lw; l < l0; ++l) {
    double xv = (double)x[(size_t)(l * B + b) * D + d];
#pragma unroll
    for (int n = 0; n < NDIM; ++n) s[n] = fma(q[n], s[n], xv);
  }
  for (int l = l0; l < l0 + CL; ++l) {
    double xv = (double)x[(size_t)(l * B + b) * D + d];
    double conv = 0.0;
#pragma unroll
    for (int n = 0; n < NDIM; ++n) {
      s[n] = fma(q[n], s[n], xv);
      conv = fma(c[n], s[n], conv);
    }
    float m = (float)(conv + xv * om);
    float sg = 1.0f / (1.0f + expf(-m));
    mx[((size_t)b * L + l) * D + d] = m * sg;   // (B,L,D)
  }
}

// ---------------- 3. logit = mx@Wp + bp (fp64), pi, sel ----------------
__global__ __launch_bounds__(256) void k_logit(const float* __restrict__ mx,
                                               const float* __restrict__ Wp,
                                               const float* __restrict__ bp,
                                               const float* __restrict__ temp,
                                               float* __restrict__ pi,
                                               int* __restrict__ selb) {
  int rid = blockIdx.x * 4 + (threadIdx.x >> 6);
  int lane = threadIdx.x & 63;
  const float* row = mx + (size_t)rid * D;
  double acc = 0.0;
#pragma unroll
  for (int i = 0; i < D / 64; ++i)
    acc += (double)row[lane + 64 * i] * (double)Wp[lane + 64 * i];
  for (int off = 32; off; off >>= 1) acc += __shfl_down(acc, off, 64);
  if (lane == 0) {
    double logit = acc + (double)bp[0];
    double scl = logit / exp((double)temp[0]);
    pi[rid] = (float)(1.0 / (1.0 + exp(-scl)));
    selb[rid] = (logit > 0.0) ? 1 : 0;
  }
}

// ---------------- 4. per-batch scan ----------------
__global__ __launch_bounds__(256) void k_scan(const int* __restrict__ selb,
                                              int* __restrict__ idx,
                                              int* __restrict__ src,
                                              int* __restrict__ counts) {
  int b = blockIdx.x;
  int t = threadIdx.x;
  __shared__ int part[256];
  const int PER = L / 256;
  int base = b * L + t * PER;
  int loc[PER];
  int cnt = 0;
#pragma unroll
  for (int i = 0; i < PER; ++i) { loc[i] = selb[base + i]; cnt += loc[i]; }
  part[t] = cnt;
  __syncthreads();
  for (int off = 1; off < 256; off <<= 1) {
    int v = (t >= off) ? part[t - off] : 0;
    __syncthreads();
    part[t] += v;
    __syncthreads();
  }
  int run = (t == 0) ? 0 : part[t - 1];
#pragma unroll
  for (int i = 0; i < PER; ++i) {
    int sflag = loc[i];
    run += sflag;
    idx[base + i] = sflag ? run : 0;
    if (sflag) src[b * L + run - 1] = t * PER + i;
  }
  if (t == 255) counts[b] = part[255];
}

// ---------------- 5. gather compacted c -> bf16 ----------------
__global__ __launch_bounds__(256) void k_buildc(const float* __restrict__ mx,
                                                const int* __restrict__ src,
                                                const int* __restrict__ counts,
                                                unsigned short* __restrict__ c) {
  int row = blockIdx.x;
  int b = row >> 13;
  int j = row & (L - 1);
  int t = threadIdx.x;
  float v0 = 0.f, v1 = 0.f;
  if (j < counts[b]) {
    const float* mr = mx + ((size_t)b * L + src[row]) * D;
    v0 = mr[t];
    v1 = mr[t + 256];
  }
  unsigned short* cr = c + (size_t)row * D;
  cr[t] = f2bf(v0);
  cr[t + 256] = f2bf(v1);
}

// ---------------- 5b. weight transpose+convert: Wt[n][k] = bf16(W[k][n]) ----------------
__global__ __launch_bounds__(256) void k_wt(const float* __restrict__ Wm,
                                            unsigned short* __restrict__ Wt, int N) {
  int idx = blockIdx.x * 256 + threadIdx.x;   // n*512 + k
  int n = idx >> 9, kk = idx & 511;
  Wt[idx] = f2bf(Wm[(size_t)kk * N + n]);
}

// ---------------- 6. bf16 MFMA GEMM + silu ----------------
__global__ __launch_bounds__(256) void k_gemm_mfma(const unsigned short* __restrict__ A,
                                                   const unsigned short* __restrict__ Bt,
                                                   float* __restrict__ outF,
                                                   unsigned short* __restrict__ outT,
                                                   int N, int mode) {
  __shared__ char As[16384];   // [128 rows][64 k] bf16, XOR-swizzled
  __shared__ char Bs[16384];
  int tid = threadIdx.x;
  int w = tid >> 6, l = tid & 63;
  int m0 = blockIdx.x * 128, n0 = blockIdx.y * 128;
  int wr = w >> 1, wc = w & 1;
  f32x4 acc[4][4];
  f32x4 zz = {0.f, 0.f, 0.f, 0.f};
#pragma unroll
  for (int mi = 0; mi < 4; ++mi)
#pragma unroll
    for (int ni = 0; ni < 4; ++ni) acc[mi][ni] = zz;

  for (int k0 = 0; k0 < 512; k0 += 64) {
#pragma unroll
    for (int ld = 0; ld < 4; ++ld) {
      int li = w * 4 + ld;                 // 0..15
      int row = li * 8 + (l >> 3);
      int col = (((l & 7) ^ (row & 7)) << 3);
      gld16(A + (size_t)(m0 + row) * 512 + k0 + col, As + li * 1024);
      gld16(Bt + (size_t)(n0 + row) * 512 + k0 + col, Bs + li * 1024);
    }
    __syncthreads();
    s16x8 af[4][2], bfr[4][2];
#pragma unroll
    for (int kh = 0; kh < 2; ++kh) {
#pragma unroll
      for (int mi = 0; mi < 4; ++mi) {
        int row = wr * 64 + mi * 16 + (l & 15);
        int byte = row * 128 + ((kh * 64 + ((l >> 4) * 16)) ^ ((row & 7) << 4));
        af[mi][kh] = *(const s16x8*)(As + byte);
      }
#pragma unroll
      for (int ni = 0; ni < 4; ++ni) {
        int row = wc * 64 + ni * 16 + (l & 15);
        int byte = row * 128 + ((kh * 64 + ((l >> 4) * 16)) ^ ((row & 7) << 4));
        bfr[ni][kh] = *(const s16x8*)(Bs + byte);
      }
    }
#pragma unroll
    for (int kh = 0; kh < 2; ++kh)
#pragma unroll
      for (int mi = 0; mi < 4; ++mi)
#pragma unroll
        for (int ni = 0; ni < 4; ++ni)
          acc[mi][ni] = __builtin_amdgcn_mfma_f32_16x16x32_bf16(af[mi][kh], bfr[ni][kh], acc[mi][ni], 0, 0, 0);
    __syncthreads();
  }
#pragma unroll
  for (int mi = 0; mi < 4; ++mi)
#pragma unroll
    for (int ni = 0; ni < 4; ++ni)
#pragma unroll
      for (int r = 0; r < 4; ++r) {
        float vv = acc[mi][ni][r];
        vv = vv / (1.0f + __expf(-vv));     // silu
        int mrow = m0 + wr * 64 + mi * 16 + (l >> 4) * 4 + r;
        int ncol = n0 + wc * 64 + ni * 16 + (l & 15);
        if (mode == 0) {
          outF[(size_t)mrow * N + ncol] = vv;
        } else {
          int b = mrow >> 13, j = mrow & 8191;
          outT[((size_t)(b * 512 + ncol)) * 8192 + j] = f2bf(vv);
        }
      }
}

// ---------------- 7. rotary -> bf16 q/k ----------------
__global__ __launch_bounds__(256) void k_rot(const float* __restrict__ z,
                                             const float* __restrict__ qg,
                                             const float* __restrict__ qb,
                                             const float* __restrict__ kg,
                                             const float* __restrict__ kb,
                                             unsigned short* __restrict__ qo,
                                             unsigned short* __restrict__ ko) {
  int tid = blockIdx.x * 256 + threadIdx.x;
  int i = tid & 63;
  int row = tid >> 6;
  int j = row & (L - 1);
  double freq = exp(((double)(-2 * i) / 128.0) * log(10000.0));
  float angf = (float)j * (float)freq;
  double sa, ca;
  sincos((double)angf, &sa, &ca);
  float cc = (float)ca, ss = (float)sa;
  size_t base = (size_t)row * Z + 2 * i;
  float z1 = z[base], z2 = z[base + 1];
  float q1 = z1 * qg[2 * i] + qb[2 * i], q2 = z2 * qg[2 * i + 1] + qb[2 * i + 1];
  float k1 = z1 * kg[2 * i] + kb[2 * i], k2 = z2 * kg[2 * i + 1] + kb[2 * i + 1];
  qo[base]     = f2bf(q1 * cc - q2 * ss);
  qo[base + 1] = f2bf(q1 * ss + q2 * cc);
  ko[base]     = f2bf(k1 * cc - k2 * ss);
  ko[base + 1] = f2bf(k1 * ss + k2 * cc);
}

// ---------------- 8. MFMA windowed attention ----------------
__global__ __launch_bounds__(512) void k_attn_mfma(const unsigned short* __restrict__ q,
                                                   const unsigned short* __restrict__ k,
                                                   const unsigned short* __restrict__ vT,
                                                   const float* __restrict__ relb,
                                                   const int* __restrict__ counts,
                                                   float* __restrict__ h) {
  __shared__ char smem[131072];
  char* Qs = smem;
  char* Ks = smem + 32768;
  char* Ps = smem;
  char* Vs = smem + 65536;
  int tid = threadIdx.x, w = tid >> 6, l = tid & 63;
  int n = blockIdx.x & 63, b = blockIdx.x >> 6;
  int cnt = counts[b];
  int q0 = n * 128, kbase = q0 - 128;
  const size_t rowb = (size_t)b * L;

#pragma unroll
  for (int ld = 0; ld < 4; ++ld) {
    int li = w * 4 + ld;
    int row = li * 4 + (l >> 4);
    int colb = ((l & 15) * 16) ^ ((row & 7) << 4);
    gld16((const char*)(q + (rowb + q0 + row) * Z) + colb, Qs + li * 1024);
  }
#pragma unroll
  for (int ld = 0; ld < 8; ++ld) {
    int li = w * 8 + ld;
    int row = li * 4 + (l >> 4);
    int jk = kbase + row; if (jk < 0) jk = 0;
    int colb = ((l & 15) * 16) ^ ((row & 7) << 4);
    gld16((const char*)(k + (rowb + jk) * Z) + colb, Ks + li * 1024);
  }
  __syncthreads();

  int m0 = w * 16;
  f32x4 s[16];
  f32x4 zz = {0.f, 0.f, 0.f, 0.f};
#pragma unroll
  for (int ni = 0; ni < 16; ++ni) s[ni] = zz;
  s16x8 aq[4];
#pragma unroll
  for (int ks = 0; ks < 4; ++ks) {
    int row = m0 + (l & 15);
    int byte = row * 256 + ((ks * 64 + ((l >> 4) * 16)) ^ ((row & 7) << 4));
    aq[ks] = *(const s16x8*)(Qs + byte);
  }
#pragma unroll
  for (int ni = 0; ni < 16; ++ni) {
    int row = ni * 16 + (l & 15);
    int rb = row * 256, sw = (row & 7) << 4;
#pragma unroll
    for (int ks = 0; ks < 4; ++ks) {
      s16x8 bk = *(const s16x8*)(Ks + rb + ((ks * 64 + ((l >> 4) * 16)) ^ sw));
      s[ni] = __builtin_amdgcn_mfma_f32_16x16x32_bf16(aq[ks], bk, s[ni], 0, 0, 0);
    }
  }
  __syncthreads();

  auto stageV = [&](int nc) {
#pragma unroll
    for (int ld = 0; ld < 8; ++ld) {
      int li = w * 8 + ld;
      int row = li * 2 + (l >> 5);
      int colb = ((l & 31) * 16) ^ ((row & 7) << 4);
      int j = kbase + (colb >> 1);
      if (j < 0) j = 0;
      gld16((const char*)(vT + ((size_t)(b * 512 + nc * 128 + row)) * L + j), Vs + li * 1024);
    }
  };
  stageV(0);

  int rgrp = (l >> 4) * 4;
  float mxr[4] = {-3e38f, -3e38f, -3e38f, -3e38f};
#pragma unroll
  for (int ni = 0; ni < 16; ++ni) {
    int col = ni * 16 + (l & 15);
    int kabs = kbase + col;
#pragma unroll
    for (int r = 0; r < 4; ++r) {
      int ww = m0 + rgrp + r;
      bool valid = (kabs >= 0) && (kabs <= q0 + ww) && (kabs < cnt);
      float vv = valid ? (s[ni][r] * 0.08838834764831845f + relb[col + 127 - ww]) : NEGF;
      s[ni][r] = vv;
      mxr[r] = fmaxf(mxr[r], vv);
    }
  }
#pragma unroll
  for (int r = 0; r < 4; ++r)
    for (int off = 1; off < 16; off <<= 1)
      mxr[r] = fmaxf(mxr[r], __shfl_xor(mxr[r], off, 64));
  float smr[4] = {0.f, 0.f, 0.f, 0.f};
#pragma unroll
  for (int ni = 0; ni < 16; ++ni)
#pragma unroll
    for (int r = 0; r < 4; ++r) {
      float p = __expf(s[ni][r] - mxr[r]);
      s[ni][r] = p;
      smr[r] += p;
    }
#pragma unroll
  for (int r = 0; r < 4; ++r) {
    for (int off = 1; off < 16; off <<= 1) smr[r] += __shfl_xor(smr[r], off, 64);
    smr[r] = 1.0f / smr[r];
  }
#pragma unroll
  for (int ni = 0; ni < 16; ++ni) {
    int colb2 = (ni * 16 + (l & 15)) * 2;
#pragma unroll
    for (int r = 0; r < 4; ++r) {
      int row = m0 + rgrp + r;
      *(unsigned short*)(Ps + row * 512 + (colb2 ^ ((row & 7) << 4))) = f2bf(s[ni][r] * smr[r]);
    }
  }
  __syncthreads();

  for (int nc = 0; nc < 4; ++nc) {
    if (nc) {
      __syncthreads();
      stageV(nc);
      __syncthreads();
    }
    f32x4 o[8];
#pragma unroll
    for (int ni = 0; ni < 8; ++ni) o[ni] = zz;
    int prow = m0 + (l & 15);
    int psw = (prow & 7) << 4;
#pragma unroll
    for (int kt = 0; kt < 4; ++kt) {
      s16x8 pa0 = *(const s16x8*)(Ps + prow * 512 + ((kt * 128 + ((l >> 4) * 16)) ^ psw));
      s16x8 pa1 = *(const s16x8*)(Ps + prow * 512 + ((kt * 128 + 64 + ((l >> 4) * 16)) ^ psw));
#pragma unroll
      for (int ni = 0; ni < 8; ++ni) {
        int vrow = ni * 16 + (l & 15);
        int vsw = (vrow & 7) << 4;
        s16x8 vb0 = *(const s16x8*)(Vs + vrow * 512 + ((kt * 128 + ((l >> 4) * 16)) ^ vsw));
        s16x8 vb1 = *(const s16x8*)(Vs + vrow * 512 + ((kt * 128 + 64 + ((l >> 4) * 16)) ^ vsw));
        o[ni] = __builtin_amdgcn_mfma_f32_16x16x32_bf16(pa0, vb0, o[ni], 0, 0, 0);
        o[ni] = __builtin_amdgcn_mfma_f32_16x16x32_bf16(pa1, vb1, o[ni], 0, 0, 0);
      }
    }
#pragma unroll
    for (int ni = 0; ni < 8; ++ni)
#pragma unroll
      for (int r = 0; r < 4; ++r)
        h[(rowb + q0 + m0 + rgrp + r) * 512 + nc * 128 + ni * 16 + (l & 15)] = o[ni][r];
  }
}

// ---------------- 9. out = x + gather(h, idx) * pi ----------------
__global__ __launch_bounds__(256) void k_final(const float* __restrict__ x,
                                               const float* __restrict__ h,
                                               const float* __restrict__ pi,
                                               const int* __restrict__ idx,
                                               float* __restrict__ out) {
  size_t tid = (size_t)blockIdx.x * 256 + threadIdx.x;
  int d = tid & (D - 1);
  size_t rem = tid >> 9;
  int b = (int)(rem & 3);
  int l = (int)(rem >> 2);
  int ix = idx[b * L + l];
  float val = x[tid];
  if (ix > 0) val += h[((size_t)b * L + ix - 1) * D + d] * pi[b * L + l];
  out[tid] = val;
}

extern "C" void kernel_launch(void* const* d_in, const int* in_sizes, int n_in,
                              void* d_out, int out_size, void* d_ws, size_t ws_size,
                              hipStream_t stream) {
  const float* x     = (const float*)d_in[0];
  const float* delta = (const float*)d_in[1];
  const float* alpha = (const float*)d_in[2];
  const float* beta  = (const float*)d_in[3];
  const float* gamma = (const float*)d_in[4];
  const float* omega = (const float*)d_in[5];
  const float* Wp    = (const float*)d_in[6];
  const float* bp    = (const float*)d_in[7];
  const float* temp  = (const float*)d_in[8];
  const float* Wz    = (const float*)d_in[9];
  const float* qg    = (const float*)d_in[10];
  const float* qb    = (const float*)d_in[11];
  const float* kg    = (const float*)d_in[12];
  const float* kb    = (const float*)d_in[13];
  const float* Wv    = (const float*)d_in[14];
  const float* relb  = (const float*)d_in[15];
  (void)in_sizes; (void)n_in; (void)out_size; (void)ws_size;

  char* wsb = (char*)d_ws;
  size_t o = 0;
  auto alloc = [&](size_t bytes) {
    char* p = wsb + o;
    o += (bytes + 255) & ~(size_t)255;
    return p;
  };
  float* mxv           = (float*)alloc((size_t)B * L * D * 4);          // mx, reused as h
  unsigned short* cb   = (unsigned short*)alloc((size_t)B * L * D * 2); // c bf16
  float* zb            = (float*)alloc((size_t)B * L * Z * 4);
  unsigned short* qb2  = (unsigned short*)alloc((size_t)B * L * Z * 2);
  unsigned short* kb2  = (unsigned short*)alloc((size_t)B * L * Z * 2);
  unsigned short* vTb  = (unsigned short*)alloc((size_t)B * D * L * 2); // v^T [B][D][L]
  unsigned short* wzt  = (unsigned short*)alloc((size_t)Z * 512 * 2);
  unsigned short* wvt  = (unsigned short*)alloc((size_t)D * 512 * 2);
  float* pib = (float*)alloc((size_t)B * L * 4);
  int* selb  = (int*)alloc((size_t)B * L * 4);
  int* idx   = (int*)alloc((size_t)B * L * 4);
  int* src   = (int*)alloc((size_t)B * L * 4);
  int* cnt   = (int*)alloc(256);
  double* qdn = (double*)alloc((size_t)D * NDIM * 8);
  double* cdn = (double*)alloc((size_t)D * NDIM * 8);

  k_prep<<<(D * NDIM + 255) / 256, 256, 0, stream>>>(delta, alpha, beta, gamma, qdn, cdn);
  k_conv<<<(L / CL) * B * 2, 256, 0, stream>>>(x, omega, qdn, cdn, mxv);
  k_logit<<<B * L / 4, 256, 0, stream>>>(mxv, Wp, bp, temp, pib, selb);
  k_scan<<<B, 256, 0, stream>>>(selb, idx, src, cnt);
  k_buildc<<<B * L, 256, 0, stream>>>(mxv, src, cnt, cb);
  k_wt<<<Z * 512 / 256, 256, 0, stream>>>(Wz, wzt, Z);
  k_wt<<<D * 512 / 256, 256, 0, stream>>>(Wv, wvt, D);
  k_gemm_mfma<<<dim3(256, 1), 256, 0, stream>>>(cb, wzt, zb, vTb, Z, 0);
  k_gemm_mfma<<<dim3(256, 4), 256, 0, stream>>>(cb, wvt, zb, vTb, D, 1);
  k_rot<<<B * L * (Z / 2) / 256, 256, 0, stream>>>(zb, qg, qb, kg, kb, qb2, kb2);
  k_attn_mfma<<<B * 64, 512, 0, stream>>>(qb2, kb2, vTb, relb, cnt, mxv);
  k_final<<<(int)((size_t)L * B * D / 256), 256, 0, stream>>>(x, mxv, pib, idx, (float*)d_out);
}

// Round 4
// 277.378 us; speedup vs baseline: 4.6896x; 1.2673x over previous
//
#include <hip/hip_runtime.h>
#include <math.h>

constexpr int L = 8192;
constexpr int B = 4;
constexpr int D = 512;
constexpr int NDIM = 16;
constexpr int Z = 128;
constexpr float NEGF = -50000.0f;
constexpr int CCL = 64;     // conv chunk length
constexpr int NCH = L / CCL; // 128 chunks

typedef short s16x8 __attribute__((ext_vector_type(8)));
typedef float f32x4 __attribute__((ext_vector_type(4)));

typedef __attribute__((address_space(1))) const void* as1cv;
typedef __attribute__((address_space(3))) void* as3v;

__device__ __forceinline__ void gld16(const void* g, void* l) {
  __builtin_amdgcn_global_load_lds((as1cv)g, (as3v)l, 16, 0, 0);
}

__device__ __forceinline__ unsigned short f2bf(float f) {
  unsigned u = __builtin_bit_cast(unsigned, f);
  u += 0x7fffu + ((u >> 16) & 1u);
  return (unsigned short)(u >> 16);
}

// ---------------- 1. per-(d,n) decay q, coefficient c, chunk decay powers (fp64) ----------------
__global__ __launch_bounds__(256) void k_prep(const float* __restrict__ delta,
                                              const float* __restrict__ alpha,
                                              const float* __restrict__ beta,
                                              const float* __restrict__ gamma,
                                              double* __restrict__ qdn,
                                              double* __restrict__ cdn,
                                              double* __restrict__ rp1,
                                              double* __restrict__ rp2) {
  int i = blockIdx.x * 256 + threadIdx.x;
  if (i >= D * NDIM) return;
  double p = 1.0 / (1.0 + exp(-(double)delta[i]));
  double a = 1.0 / (1.0 + exp(-(double)alpha[i]));
  double q = 1.0 - p * a;
  qdn[i] = q;
  cdn[i] = p * (double)beta[i] * (double)gamma[i] * 0.25;  // scale = 1/sqrt(NDIM)
  double q2 = q * q, q4 = q2 * q2, q8 = q4 * q4;
  double q16 = q8 * q8, q32 = q16 * q16, q64 = q32 * q32;
  rp1[i] = q64;          // q^CCL
  rp2[i] = q64 * q64;    // q^(2*CCL)
}

// ---------------- 2a. conv phase A: per-chunk zero-init scan -> end states E ----------------
// block: (b, dgrp of 64, l-tile of 256).  256 thr = 64 d x 4 chunks.
__global__ __launch_bounds__(256) void k_convA(const float* __restrict__ x,
                                               const double* __restrict__ qdn,
                                               double* __restrict__ E) {
  __shared__ float xs[256 * 64];
  int bx = blockIdx.x;
  int tile = bx & 31, dg = (bx >> 5) & 7, b = bx >> 8;
  int tid = threadIdx.x;
  int tile_l0 = tile * 256;
  int d = tid & 63, cl = tid >> 6;
#pragma unroll
  for (int i = 0; i < 16; ++i) {
    int u4 = i * 256 + tid;          // float4 index into tile
    int lloc = u4 >> 4;              // 16 float4 per 64-float row
    int dl = (u4 & 15) * 4;
    gld16(x + ((size_t)(tile_l0 + lloc) * B + b) * D + dg * 64 + dl, (char*)xs + (size_t)u4 * 16);
  }
  __syncthreads();
  int dgl = dg * 64 + d;
  double q[NDIM], s[NDIM];
#pragma unroll
  for (int n = 0; n < NDIM; ++n) { q[n] = qdn[dgl * NDIM + n]; s[n] = 0.0; }
  const float* xp = xs + cl * 64 * 64 + d;
  for (int i = 0; i < CCL; ++i) {
    double xv = (double)xp[i * 64];
#pragma unroll
    for (int n = 0; n < NDIM; ++n) s[n] = fma(q[n], s[n], xv);
  }
  int t = tile * 4 + cl;
  size_t eb = ((size_t)(b * NCH + t) * NDIM) * 512 + dgl;
#pragma unroll
  for (int n = 0; n < NDIM; ++n) E[eb + (size_t)n * 512] = s[n];
}

// ---------------- 2b. conv phase C: incoming state via 3-term series, emit mx ----------------
__global__ __launch_bounds__(256) void k_convC(const float* __restrict__ x,
                                               const float* __restrict__ omega,
                                               const double* __restrict__ qdn,
                                               const double* __restrict__ cdn,
                                               const double* __restrict__ rp1,
                                               const double* __restrict__ rp2,
                                               const double* __restrict__ E,
                                               float* __restrict__ mx) {
  __shared__ float xs[256 * 64];
  int bx = blockIdx.x;
  int tile = bx & 31, dg = (bx >> 5) & 7, b = bx >> 8;
  int tid = threadIdx.x;
  int tile_l0 = tile * 256;
  int d = tid & 63, cl = tid >> 6;
#pragma unroll
  for (int i = 0; i < 16; ++i) {
    int u4 = i * 256 + tid;
    int lloc = u4 >> 4;
    int dl = (u4 & 15) * 4;
    gld16(x + ((size_t)(tile_l0 + lloc) * B + b) * D + dg * 64 + dl, (char*)xs + (size_t)u4 * 16);
  }
  int dgl = dg * 64 + d;
  int t = tile * 4 + cl;
  double q[NDIM], c[NDIM], s[NDIM];
#pragma unroll
  for (int n = 0; n < NDIM; ++n) {
    q[n] = qdn[dgl * NDIM + n];
    c[n] = cdn[dgl * NDIM + n];
    s[n] = 0.0;
  }
  // incoming state S_{t-1} = E[t-1] + q^64 E[t-2] + q^128 E[t-3]
  if (t >= 1) {
    size_t e1 = ((size_t)(b * NCH + t - 1) * NDIM) * 512 + dgl;
#pragma unroll
    for (int n = 0; n < NDIM; ++n) s[n] = E[e1 + (size_t)n * 512];
  }
  if (t >= 2) {
    size_t e2 = ((size_t)(b * NCH + t - 2) * NDIM) * 512 + dgl;
#pragma unroll
    for (int n = 0; n < NDIM; ++n) s[n] = fma(rp1[dgl * NDIM + n], E[e2 + (size_t)n * 512], s[n]);
  }
  if (t >= 3) {
    size_t e3 = ((size_t)(b * NCH + t - 3) * NDIM) * 512 + dgl;
#pragma unroll
    for (int n = 0; n < NDIM; ++n) s[n] = fma(rp2[dgl * NDIM + n], E[e3 + (size_t)n * 512], s[n]);
  }
  double om = (double)omega[dgl];
  __syncthreads();
  const float* xp = xs + cl * 64 * 64 + d;
  float* mrow = mx + ((size_t)b * L + t * CCL) * 512 + dgl;
  for (int i = 0; i < CCL; ++i) {
    double xv = (double)xp[i * 64];
#pragma unroll
    for (int n = 0; n < NDIM; ++n) s[n] = fma(q[n], s[n], xv);
    double p0 = c[0] * s[0], p1 = c[1] * s[1], p2 = c[2] * s[2], p3 = c[3] * s[3];
    p0 = fma(c[4], s[4], p0);  p1 = fma(c[5], s[5], p1);
    p2 = fma(c[6], s[6], p2);  p3 = fma(c[7], s[7], p3);
    p0 = fma(c[8], s[8], p0);  p1 = fma(c[9], s[9], p1);
    p2 = fma(c[10], s[10], p2); p3 = fma(c[11], s[11], p3);
    p0 = fma(c[12], s[12], p0); p1 = fma(c[13], s[13], p1);
    p2 = fma(c[14], s[14], p2); p3 = fma(c[15], s[15], p3);
    double conv = (p0 + p1) + (p2 + p3);
    float m = (float)(conv + xv * om);
    float sg = 1.0f / (1.0f + expf(-m));
    mrow[(size_t)i * 512] = m * sg;
  }
}

// ---------------- 3. logit = mx@Wp + bp (fp64), pi, sel ----------------
__global__ __launch_bounds__(256) void k_logit(const float* __restrict__ mx,
                                               const float* __restrict__ Wp,
                                               const float* __restrict__ bp,
                                               const float* __restrict__ temp,
                                               float* __restrict__ pi,
                                               int* __restrict__ selb) {
  int rid = blockIdx.x * 4 + (threadIdx.x >> 6);
  int lane = threadIdx.x & 63;
  const float* row = mx + (size_t)rid * D;
  double acc = 0.0;
#pragma unroll
  for (int i = 0; i < D / 64; ++i)
    acc += (double)row[lane + 64 * i] * (double)Wp[lane + 64 * i];
  for (int off = 32; off; off >>= 1) acc += __shfl_down(acc, off, 64);
  if (lane == 0) {
    double logit = acc + (double)bp[0];
    double scl = logit / exp((double)temp[0]);
    pi[rid] = (float)(1.0 / (1.0 + exp(-scl)));
    selb[rid] = (logit > 0.0) ? 1 : 0;
  }
}

// ---------------- 4. per-batch scan ----------------
__global__ __launch_bounds__(256) void k_scan(const int* __restrict__ selb,
                                              int* __restrict__ idx,
                                              int* __restrict__ src,
                                              int* __restrict__ counts) {
  int b = blockIdx.x;
  int t = threadIdx.x;
  __shared__ int part[256];
  const int PER = L / 256;
  int base = b * L + t * PER;
  int loc[PER];
  int cnt = 0;
#pragma unroll
  for (int i = 0; i < PER; ++i) { loc[i] = selb[base + i]; cnt += loc[i]; }
  part[t] = cnt;
  __syncthreads();
  for (int off = 1; off < 256; off <<= 1) {
    int v = (t >= off) ? part[t - off] : 0;
    __syncthreads();
    part[t] += v;
    __syncthreads();
  }
  int run = (t == 0) ? 0 : part[t - 1];
#pragma unroll
  for (int i = 0; i < PER; ++i) {
    int sflag = loc[i];
    run += sflag;
    idx[base + i] = sflag ? run : 0;
    if (sflag) src[b * L + run - 1] = t * PER + i;
  }
  if (t == 255) counts[b] = part[255];
}

// ---------------- 5. gather compacted c -> bf16 (vectorized) ----------------
__global__ __launch_bounds__(256) void k_buildc(const float* __restrict__ mx,
                                                const int* __restrict__ src,
                                                const int* __restrict__ counts,
                                                unsigned short* __restrict__ c) {
  int row = blockIdx.x * 4 + (threadIdx.x >> 6);
  int lane = threadIdx.x & 63;
  int b = row >> 13;
  int j = row & (L - 1);
  float4 v0 = {0.f, 0.f, 0.f, 0.f}, v1 = v0;
  if (j < counts[b]) {
    const float4* mr = (const float4*)(mx + ((size_t)b * L + src[row]) * D);
    v0 = mr[lane * 2];
    v1 = mr[lane * 2 + 1];
  }
  s16x8 o;
  o[0] = (short)f2bf(v0.x); o[1] = (short)f2bf(v0.y);
  o[2] = (short)f2bf(v0.z); o[3] = (short)f2bf(v0.w);
  o[4] = (short)f2bf(v1.x); o[5] = (short)f2bf(v1.y);
  o[6] = (short)f2bf(v1.z); o[7] = (short)f2bf(v1.w);
  *(s16x8*)(c + (size_t)row * D + lane * 8) = o;
}

// ---------------- 5b. weight transpose+convert ----------------
__global__ __launch_bounds__(256) void k_wt(const float* __restrict__ Wm,
                                            unsigned short* __restrict__ Wt, int N) {
  int idx = blockIdx.x * 256 + threadIdx.x;   // n*512 + k
  int n = idx >> 9, kk = idx & 511;
  Wt[idx] = f2bf(Wm[(size_t)kk * N + n]);
}

// ---------------- 6. bf16 MFMA GEMM + silu ----------------
__global__ __launch_bounds__(256) void k_gemm_mfma(const unsigned short* __restrict__ A,
                                                   const unsigned short* __restrict__ Bt,
                                                   float* __restrict__ outF,
                                                   unsigned short* __restrict__ outT,
                                                   int N, int mode) {
  __shared__ char As[16384];   // [128 rows][64 k] bf16, XOR-swizzled
  __shared__ char Bs[16384];
  int tid = threadIdx.x;
  int w = tid >> 6, l = tid & 63;
  int m0 = blockIdx.x * 128, n0 = blockIdx.y * 128;
  int wr = w >> 1, wc = w & 1;
  f32x4 acc[4][4];
  f32x4 zz = {0.f, 0.f, 0.f, 0.f};
#pragma unroll
  for (int mi = 0; mi < 4; ++mi)
#pragma unroll
    for (int ni = 0; ni < 4; ++ni) acc[mi][ni] = zz;

  for (int k0 = 0; k0 < 512; k0 += 64) {
#pragma unroll
    for (int ld = 0; ld < 4; ++ld) {
      int li = w * 4 + ld;
      int row = li * 8 + (l >> 3);
      int col = (((l & 7) ^ (row & 7)) << 3);
      gld16(A + (size_t)(m0 + row) * 512 + k0 + col, As + li * 1024);
      gld16(Bt + (size_t)(n0 + row) * 512 + k0 + col, Bs + li * 1024);
    }
    __syncthreads();
    s16x8 af[4][2], bfr[4][2];
#pragma unroll
    for (int kh = 0; kh < 2; ++kh) {
#pragma unroll
      for (int mi = 0; mi < 4; ++mi) {
        int row = wr * 64 + mi * 16 + (l & 15);
        int byte = row * 128 + ((kh * 64 + ((l >> 4) * 16)) ^ ((row & 7) << 4));
        af[mi][kh] = *(const s16x8*)(As + byte);
      }
#pragma unroll
      for (int ni = 0; ni < 4; ++ni) {
        int row = wc * 64 + ni * 16 + (l & 15);
        int byte = row * 128 + ((kh * 64 + ((l >> 4) * 16)) ^ ((row & 7) << 4));
        bfr[ni][kh] = *(const s16x8*)(Bs + byte);
      }
    }
#pragma unroll
    for (int kh = 0; kh < 2; ++kh)
#pragma unroll
      for (int mi = 0; mi < 4; ++mi)
#pragma unroll
        for (int ni = 0; ni < 4; ++ni)
          acc[mi][ni] = __builtin_amdgcn_mfma_f32_16x16x32_bf16(af[mi][kh], bfr[ni][kh], acc[mi][ni], 0, 0, 0);
    __syncthreads();
  }
#pragma unroll
  for (int mi = 0; mi < 4; ++mi)
#pragma unroll
    for (int ni = 0; ni < 4; ++ni)
#pragma unroll
      for (int r = 0; r < 4; ++r) {
        float vv = acc[mi][ni][r];
        vv = vv / (1.0f + __expf(-vv));     // silu
        int mrow = m0 + wr * 64 + mi * 16 + (l >> 4) * 4 + r;
        int ncol = n0 + wc * 64 + ni * 16 + (l & 15);
        if (mode == 0) {
          outF[(size_t)mrow * N + ncol] = vv;
        } else {
          int b = mrow >> 13, j = mrow & 8191;
          outT[((size_t)(b * 512 + ncol)) * 8192 + j] = f2bf(vv);
        }
      }
}

// ---------------- 7. rotary -> bf16 q/k ----------------
__global__ __launch_bounds__(256) void k_rot(const float* __restrict__ z,
                                             const float* __restrict__ qg,
                                             const float* __restrict__ qb,
                                             const float* __restrict__ kg,
                                             const float* __restrict__ kb,
                                             unsigned short* __restrict__ qo,
                                             unsigned short* __restrict__ ko) {
  int tid = blockIdx.x * 256 + threadIdx.x;
  int i = tid & 63;
  int row = tid >> 6;
  int j = row & (L - 1);
  double freq = exp(((double)(-2 * i) / 128.0) * log(10000.0));
  float angf = (float)j * (float)freq;
  double sa, ca;
  sincos((double)angf, &sa, &ca);
  float cc = (float)ca, ss = (float)sa;
  size_t base = (size_t)row * Z + 2 * i;
  float z1 = z[base], z2 = z[base + 1];
  float q1 = z1 * qg[2 * i] + qb[2 * i], q2 = z2 * qg[2 * i + 1] + qb[2 * i + 1];
  float k1 = z1 * kg[2 * i] + kb[2 * i], k2 = z2 * kg[2 * i + 1] + kb[2 * i + 1];
  qo[base]     = f2bf(q1 * cc - q2 * ss);
  qo[base + 1] = f2bf(q1 * ss + q2 * cc);
  ko[base]     = f2bf(k1 * cc - k2 * ss);
  ko[base + 1] = f2bf(k1 * ss + k2 * cc);
}

// ---------------- 8. MFMA windowed attention ----------------
__global__ __launch_bounds__(512) void k_attn_mfma(const unsigned short* __restrict__ q,
                                                   const unsigned short* __restrict__ k,
                                                   const unsigned short* __restrict__ vT,
                                                   const float* __restrict__ relb,
                                                   const int* __restrict__ counts,
                                                   float* __restrict__ h) {
  __shared__ char smem[131072];
  char* Qs = smem;
  char* Ks = smem + 32768;
  char* Ps = smem;
  char* Vs = smem + 65536;
  int tid = threadIdx.x, w = tid >> 6, l = tid & 63;
  int n = blockIdx.x & 63, b = blockIdx.x >> 6;
  int cnt = counts[b];
  int q0 = n * 128, kbase = q0 - 128;
  const size_t rowb = (size_t)b * L;

#pragma unroll
  for (int ld = 0; ld < 4; ++ld) {
    int li = w * 4 + ld;
    int row = li * 4 + (l >> 4);
    int colb = ((l & 15) * 16) ^ ((row & 7) << 4);
    gld16((const char*)(q + (rowb + q0 + row) * Z) + colb, Qs + li * 1024);
  }
#pragma unroll
  for (int ld = 0; ld < 8; ++ld) {
    int li = w * 8 + ld;
    int row = li * 4 + (l >> 4);
    int jk = kbase + row; if (jk < 0) jk = 0;
    int colb = ((l & 15) * 16) ^ ((row & 7) << 4);
    gld16((const char*)(k + (rowb + jk) * Z) + colb, Ks + li * 1024);
  }
  __syncthreads();

  int m0 = w * 16;
  f32x4 s[16];
  f32x4 zz = {0.f, 0.f, 0.f, 0.f};
#pragma unroll
  for (int ni = 0; ni < 16; ++ni) s[ni] = zz;
  s16x8 aq[4];
#pragma unroll
  for (int ks = 0; ks < 4; ++ks) {
    int row = m0 + (l & 15);
    int byte = row * 256 + ((ks * 64 + ((l >> 4) * 16)) ^ ((row & 7) << 4));
    aq[ks] = *(const s16x8*)(Qs + byte);
  }
#pragma unroll
  for (int ni = 0; ni < 16; ++ni) {
    int row = ni * 16 + (l & 15);
    int rb = row * 256, sw = (row & 7) << 4;
#pragma unroll
    for (int ks = 0; ks < 4; ++ks) {
      s16x8 bk = *(const s16x8*)(Ks + rb + ((ks * 64 + ((l >> 4) * 16)) ^ sw));
      s[ni] = __builtin_amdgcn_mfma_f32_16x16x32_bf16(aq[ks], bk, s[ni], 0, 0, 0);
    }
  }
  __syncthreads();

  auto stageV = [&](int nc) {
#pragma unroll
    for (int ld = 0; ld < 8; ++ld) {
      int li = w * 8 + ld;
      int row = li * 2 + (l >> 5);
      int colb = ((l & 31) * 16) ^ ((row & 7) << 4);
      int j = kbase + (colb >> 1);
      if (j < 0) j = 0;
      gld16((const char*)(vT + ((size_t)(b * 512 + nc * 128 + row)) * L + j), Vs + li * 1024);
    }
  };
  stageV(0);

  int rgrp = (l >> 4) * 4;
  float mxr[4] = {-3e38f, -3e38f, -3e38f, -3e38f};
#pragma unroll
  for (int ni = 0; ni < 16; ++ni) {
    int col = ni * 16 + (l & 15);
    int kabs = kbase + col;
#pragma unroll
    for (int r = 0; r < 4; ++r) {
      int ww = m0 + rgrp + r;
      bool valid = (kabs >= 0) && (kabs <= q0 + ww) && (kabs < cnt);
      float vv = valid ? (s[ni][r] * 0.08838834764831845f + relb[col + 127 - ww]) : NEGF;
      s[ni][r] = vv;
      mxr[r] = fmaxf(mxr[r], vv);
    }
  }
#pragma unroll
  for (int r = 0; r < 4; ++r)
    for (int off = 1; off < 16; off <<= 1)
      mxr[r] = fmaxf(mxr[r], __shfl_xor(mxr[r], off, 64));
  float smr[4] = {0.f, 0.f, 0.f, 0.f};
#pragma unroll
  for (int ni = 0; ni < 16; ++ni)
#pragma unroll
    for (int r = 0; r < 4; ++r) {
      float p = __expf(s[ni][r] - mxr[r]);
      s[ni][r] = p;
      smr[r] += p;
    }
#pragma unroll
  for (int r = 0; r < 4; ++r) {
    for (int off = 1; off < 16; off <<= 1) smr[r] += __shfl_xor(smr[r], off, 64);
    smr[r] = 1.0f / smr[r];
  }
#pragma unroll
  for (int ni = 0; ni < 16; ++ni) {
    int colb2 = (ni * 16 + (l & 15)) * 2;
#pragma unroll
    for (int r = 0; r < 4; ++r) {
      int row = m0 + rgrp + r;
      *(unsigned short*)(Ps + row * 512 + (colb2 ^ ((row & 7) << 4))) = f2bf(s[ni][r] * smr[r]);
    }
  }
  __syncthreads();

  for (int nc = 0; nc < 4; ++nc) {
    if (nc) {
      __syncthreads();
      stageV(nc);
      __syncthreads();
    }
    f32x4 o[8];
#pragma unroll
    for (int ni = 0; ni < 8; ++ni) o[ni] = zz;
    int prow = m0 + (l & 15);
    int psw = (prow & 7) << 4;
#pragma unroll
    for (int kt = 0; kt < 4; ++kt) {
      s16x8 pa0 = *(const s16x8*)(Ps + prow * 512 + ((kt * 128 + ((l >> 4) * 16)) ^ psw));
      s16x8 pa1 = *(const s16x8*)(Ps + prow * 512 + ((kt * 128 + 64 + ((l >> 4) * 16)) ^ psw));
#pragma unroll
      for (int ni = 0; ni < 8; ++ni) {
        int vrow = ni * 16 + (l & 15);
        int vsw = (vrow & 7) << 4;
        s16x8 vb0 = *(const s16x8*)(Vs + vrow * 512 + ((kt * 128 + ((l >> 4) * 16)) ^ vsw));
        s16x8 vb1 = *(const s16x8*)(Vs + vrow * 512 + ((kt * 128 + 64 + ((l >> 4) * 16)) ^ vsw));
        o[ni] = __builtin_amdgcn_mfma_f32_16x16x32_bf16(pa0, vb0, o[ni], 0, 0, 0);
        o[ni] = __builtin_amdgcn_mfma_f32_16x16x32_bf16(pa1, vb1, o[ni], 0, 0, 0);
      }
    }
#pragma unroll
    for (int ni = 0; ni < 8; ++ni)
#pragma unroll
      for (int r = 0; r < 4; ++r)
        h[(rowb + q0 + m0 + rgrp + r) * 512 + nc * 128 + ni * 16 + (l & 15)] = o[ni][r];
  }
}

// ---------------- 9. out = x + gather(h, idx) * pi  (float4) ----------------
__global__ __launch_bounds__(256) void k_final(const float* __restrict__ x,
                                               const float* __restrict__ h,
                                               const float* __restrict__ pi,
                                               const int* __restrict__ idx,
                                               float* __restrict__ out) {
  int e4 = blockIdx.x * 256 + threadIdx.x;     // float4 index
  int dq = e4 & 127;
  int rem = e4 >> 7;                            // l*B + b
  int b = rem & 3;
  int l = rem >> 2;
  float4 xv = ((const float4*)x)[e4];
  int ix = idx[(b << 13) + l];
  if (ix > 0) {
    float pv = pi[(b << 13) + l];
    float4 hv = ((const float4*)(h + ((size_t)(b << 13) + ix - 1) * 512))[dq];
    xv.x += hv.x * pv; xv.y += hv.y * pv;
    xv.z += hv.z * pv; xv.w += hv.w * pv;
  }
  ((float4*)out)[e4] = xv;
}

extern "C" void kernel_launch(void* const* d_in, const int* in_sizes, int n_in,
                              void* d_out, int out_size, void* d_ws, size_t ws_size,
                              hipStream_t stream) {
  const float* x     = (const float*)d_in[0];
  const float* delta = (const float*)d_in[1];
  const float* alpha = (const float*)d_in[2];
  const float* beta  = (const float*)d_in[3];
  const float* gamma = (const float*)d_in[4];
  const float* omega = (const float*)d_in[5];
  const float* Wp    = (const float*)d_in[6];
  const float* bp    = (const float*)d_in[7];
  const float* temp  = (const float*)d_in[8];
  const float* Wz    = (const float*)d_in[9];
  const float* qg    = (const float*)d_in[10];
  const float* qb    = (const float*)d_in[11];
  const float* kg    = (const float*)d_in[12];
  const float* kb    = (const float*)d_in[13];
  const float* Wv    = (const float*)d_in[14];
  const float* relb  = (const float*)d_in[15];
  (void)in_sizes; (void)n_in; (void)out_size; (void)ws_size;

  char* wsb = (char*)d_ws;
  size_t o = 0;
  auto alloc = [&](size_t bytes) {
    char* p = wsb + o;
    o += (bytes + 255) & ~(size_t)255;
    return p;
  };
  float* mxv           = (float*)alloc((size_t)B * L * D * 4);          // mx, reused as h
  // E (33.6 MB, dead after k_convC) aliases with cb (32 MB, written after)
  char*  eAndCb        = alloc((size_t)B * NCH * NDIM * 512 * 8);
  double* Ebuf         = (double*)eAndCb;
  unsigned short* cb   = (unsigned short*)eAndCb;                       // c bf16
  float* zb            = (float*)alloc((size_t)B * L * Z * 4);
  unsigned short* qb2  = (unsigned short*)alloc((size_t)B * L * Z * 2);
  unsigned short* kb2  = (unsigned short*)alloc((size_t)B * L * Z * 2);
  unsigned short* vTb  = (unsigned short*)alloc((size_t)B * D * L * 2); // v^T [B][D][L]
  unsigned short* wzt  = (unsigned short*)alloc((size_t)Z * 512 * 2);
  unsigned short* wvt  = (unsigned short*)alloc((size_t)D * 512 * 2);
  float* pib = (float*)alloc((size_t)B * L * 4);
  int* selb  = (int*)alloc((size_t)B * L * 4);
  int* idx   = (int*)alloc((size_t)B * L * 4);
  int* src   = (int*)alloc((size_t)B * L * 4);
  int* cnt   = (int*)alloc(256);
  double* qdn = (double*)alloc((size_t)D * NDIM * 8);
  double* cdn = (double*)alloc((size_t)D * NDIM * 8);
  double* rp1 = (double*)alloc((size_t)D * NDIM * 8);
  double* rp2 = (double*)alloc((size_t)D * NDIM * 8);

  k_prep<<<(D * NDIM + 255) / 256, 256, 0, stream>>>(delta, alpha, beta, gamma, qdn, cdn, rp1, rp2);
  k_convA<<<B * 8 * 32, 256, 0, stream>>>(x, qdn, Ebuf);
  k_convC<<<B * 8 * 32, 256, 0, stream>>>(x, omega, qdn, cdn, rp1, rp2, Ebuf, mxv);
  k_logit<<<B * L / 4, 256, 0, stream>>>(mxv, Wp, bp, temp, pib, selb);
  k_scan<<<B, 256, 0, stream>>>(selb, idx, src, cnt);
  k_buildc<<<B * L / 4, 256, 0, stream>>>(mxv, src, cnt, cb);
  k_wt<<<Z * 512 / 256, 256, 0, stream>>>(Wz, wzt, Z);
  k_wt<<<D * 512 / 256, 256, 0, stream>>>(Wv, wvt, D);
  k_gemm_mfma<<<dim3(256, 1), 256, 0, stream>>>(cb, wzt, zb, vTb, Z, 0);
  k_gemm_mfma<<<dim3(256, 4), 256, 0, stream>>>(cb, wvt, zb, vTb, D, 1);
  k_rot<<<B * L * (Z / 2) / 256, 256, 0, stream>>>(zb, qg, qb, kg, kb, qb2, kb2);
  k_attn_mfma<<<B * 64, 512, 0, stream>>>(qb2, kb2, vTb, relb, cnt, mxv);
  k_final<<<(int)((size_t)L * B * D / 4 / 256), 256, 0, stream>>>(x, mxv, pib, idx, (float*)d_out);
}

// Round 5
// 270.484 us; speedup vs baseline: 4.8091x; 1.0255x over previous
//
#include <hip/hip_runtime.h>
#include <math.h>

constexpr int L = 8192;
constexpr int B = 4;
constexpr int D = 512;
constexpr int NDIM = 16;
constexpr int Z = 128;
constexpr float NEGF = -50000.0f;
constexpr int CCL = 64;     // conv chunk length
constexpr int NCH = L / CCL; // 128 chunks

typedef short s16x8 __attribute__((ext_vector_type(8)));
typedef float f32x4 __attribute__((ext_vector_type(4)));

typedef __attribute__((address_space(1))) const void* as1cv;
typedef __attribute__((address_space(3))) void* as3v;

__device__ __forceinline__ void gld16(const void* g, void* l) {
  __builtin_amdgcn_global_load_lds((as1cv)g, (as3v)l, 16, 0, 0);
}

__device__ __forceinline__ unsigned short f2bf(float f) {
  unsigned u = __builtin_bit_cast(unsigned, f);
  u += 0x7fffu + ((u >> 16) & 1u);
  return (unsigned short)(u >> 16);
}

// ---------------- 1. per-(d,n) decay q, coefficient c, chunk decay powers (fp64) ----------------
__global__ __launch_bounds__(256) void k_prep(const float* __restrict__ delta,
                                              const float* __restrict__ alpha,
                                              const float* __restrict__ beta,
                                              const float* __restrict__ gamma,
                                              double* __restrict__ qdn,
                                              double* __restrict__ cdn,
                                              double* __restrict__ rp1,
                                              double* __restrict__ rp2) {
  int i = blockIdx.x * 256 + threadIdx.x;
  if (i >= D * NDIM) return;
  double p = 1.0 / (1.0 + exp(-(double)delta[i]));
  double a = 1.0 / (1.0 + exp(-(double)alpha[i]));
  double q = 1.0 - p * a;
  qdn[i] = q;
  cdn[i] = p * (double)beta[i] * (double)gamma[i] * 0.25;  // scale = 1/sqrt(NDIM)
  double q2 = q * q, q4 = q2 * q2, q8 = q4 * q4;
  double q16 = q8 * q8, q32 = q16 * q16, q64 = q32 * q32;
  rp1[i] = q64;          // q^CCL
  rp2[i] = q64 * q64;    // q^(2*CCL)
}

// ---------------- 2a. conv phase A: per-chunk zero-init scan -> end states E (fp32) ----------------
// no LDS: lane = d so the per-step wave load of x is already coalesced (256 B).
__global__ __launch_bounds__(256) void k_convA(const float* __restrict__ x,
                                               const double* __restrict__ qdn,
                                               float* __restrict__ E) {
  int bx = blockIdx.x;
  int tile = bx & 31, dg = (bx >> 5) & 7, b = bx >> 8;
  int d = threadIdx.x & 63, cl = threadIdx.x >> 6;
  int dgl = dg * 64 + d;
  int t = tile * 4 + cl;
  double q[NDIM], s[NDIM];
#pragma unroll
  for (int n = 0; n < NDIM; ++n) { q[n] = qdn[dgl * NDIM + n]; s[n] = 0.0; }
  const float* xp = x + ((size_t)(t * CCL) * B + b) * D + dgl;
#pragma unroll 4
  for (int i = 0; i < CCL; ++i) {
    double xv = (double)xp[(size_t)i * (B * D)];
#pragma unroll
    for (int n = 0; n < NDIM; ++n) s[n] = fma(q[n], s[n], xv);
  }
  float* eb = E + ((size_t)(b * NCH + t) * NDIM) * 512 + dgl;
#pragma unroll
  for (int n = 0; n < NDIM; ++n) eb[(size_t)n * 512] = (float)s[n];
}

// ---------------- 2b. conv phase C: incoming state via 3-term series, emit mx ----------------
__global__ __launch_bounds__(256) void k_convC(const float* __restrict__ x,
                                               const float* __restrict__ omega,
                                               const double* __restrict__ qdn,
                                               const double* __restrict__ cdn,
                                               const double* __restrict__ rp1,
                                               const double* __restrict__ rp2,
                                               const float* __restrict__ E,
                                               float* __restrict__ mx) {
  int bx = blockIdx.x;
  int tile = bx & 31, dg = (bx >> 5) & 7, b = bx >> 8;
  int d = threadIdx.x & 63, cl = threadIdx.x >> 6;
  int dgl = dg * 64 + d;
  int t = tile * 4 + cl;
  double q[NDIM], c[NDIM], s[NDIM];
#pragma unroll
  for (int n = 0; n < NDIM; ++n) {
    q[n] = qdn[dgl * NDIM + n];
    c[n] = cdn[dgl * NDIM + n];
    s[n] = 0.0;
  }
  // incoming state S_{t-1} = E[t-1] + q^64 E[t-2] + q^128 E[t-3]
  if (t >= 1) {
    const float* e1 = E + ((size_t)(b * NCH + t - 1) * NDIM) * 512 + dgl;
#pragma unroll
    for (int n = 0; n < NDIM; ++n) s[n] = (double)e1[(size_t)n * 512];
  }
  if (t >= 2) {
    const float* e2 = E + ((size_t)(b * NCH + t - 2) * NDIM) * 512 + dgl;
#pragma unroll
    for (int n = 0; n < NDIM; ++n) s[n] = fma(rp1[dgl * NDIM + n], (double)e2[(size_t)n * 512], s[n]);
  }
  if (t >= 3) {
    const float* e3 = E + ((size_t)(b * NCH + t - 3) * NDIM) * 512 + dgl;
#pragma unroll
    for (int n = 0; n < NDIM; ++n) s[n] = fma(rp2[dgl * NDIM + n], (double)e3[(size_t)n * 512], s[n]);
  }
  double om = (double)omega[dgl];
  const float* xp = x + ((size_t)(t * CCL) * B + b) * D + dgl;
  float* mp = mx + ((size_t)b * L + t * CCL) * 512 + dgl;
#pragma unroll 4
  for (int i = 0; i < CCL; ++i) {
    double xv = (double)xp[(size_t)i * (B * D)];
#pragma unroll
    for (int n = 0; n < NDIM; ++n) s[n] = fma(q[n], s[n], xv);
    double p0 = c[0] * s[0], p1 = c[1] * s[1], p2 = c[2] * s[2], p3 = c[3] * s[3];
    p0 = fma(c[4], s[4], p0);  p1 = fma(c[5], s[5], p1);
    p2 = fma(c[6], s[6], p2);  p3 = fma(c[7], s[7], p3);
    p0 = fma(c[8], s[8], p0);  p1 = fma(c[9], s[9], p1);
    p2 = fma(c[10], s[10], p2); p3 = fma(c[11], s[11], p3);
    p0 = fma(c[12], s[12], p0); p1 = fma(c[13], s[13], p1);
    p2 = fma(c[14], s[14], p2); p3 = fma(c[15], s[15], p3);
    double conv = (p0 + p1) + (p2 + p3);
    float m = (float)(conv + xv * om);
    float sg = 1.0f / (1.0f + expf(-m));
    mp[(size_t)i * 512] = m * sg;
  }
}

// ---------------- 3. logit = mx@Wp + bp (fp64), pi, sel ----------------
__global__ __launch_bounds__(256) void k_logit(const float* __restrict__ mx,
                                               const float* __restrict__ Wp,
                                               const float* __restrict__ bp,
                                               const float* __restrict__ temp,
                                               float* __restrict__ pi,
                                               int* __restrict__ selb) {
  int rid = blockIdx.x * 4 + (threadIdx.x >> 6);
  int lane = threadIdx.x & 63;
  const float* row = mx + (size_t)rid * D;
  double acc = 0.0;
#pragma unroll
  for (int i = 0; i < D / 64; ++i)
    acc += (double)row[lane + 64 * i] * (double)Wp[lane + 64 * i];
  for (int off = 32; off; off >>= 1) acc += __shfl_down(acc, off, 64);
  if (lane == 0) {
    double logit = acc + (double)bp[0];
    double scl = logit / exp((double)temp[0]);
    pi[rid] = (float)(1.0 / (1.0 + exp(-scl)));
    selb[rid] = (logit > 0.0) ? 1 : 0;
  }
}

// ---------------- 4. per-batch scan ----------------
__global__ __launch_bounds__(256) void k_scan(const int* __restrict__ selb,
                                              int* __restrict__ idx,
                                              int* __restrict__ src,
                                              int* __restrict__ counts) {
  int b = blockIdx.x;
  int t = threadIdx.x;
  __shared__ int part[256];
  const int PER = L / 256;
  int base = b * L + t * PER;
  int loc[PER];
  int cnt = 0;
#pragma unroll
  for (int i = 0; i < PER; ++i) { loc[i] = selb[base + i]; cnt += loc[i]; }
  part[t] = cnt;
  __syncthreads();
  for (int off = 1; off < 256; off <<= 1) {
    int v = (t >= off) ? part[t - off] : 0;
    __syncthreads();
    part[t] += v;
    __syncthreads();
  }
  int run = (t == 0) ? 0 : part[t - 1];
#pragma unroll
  for (int i = 0; i < PER; ++i) {
    int sflag = loc[i];
    run += sflag;
    idx[base + i] = sflag ? run : 0;
    if (sflag) src[b * L + run - 1] = t * PER + i;
  }
  if (t == 255) counts[b] = part[255];
}

// ---------------- 5. gather compacted c -> bf16 (vectorized) ----------------
__global__ __launch_bounds__(256) void k_buildc(const float* __restrict__ mx,
                                                const int* __restrict__ src,
                                                const int* __restrict__ counts,
                                                unsigned short* __restrict__ c) {
  int row = blockIdx.x * 4 + (threadIdx.x >> 6);
  int lane = threadIdx.x & 63;
  int b = row >> 13;
  int j = row & (L - 1);
  float4 v0 = {0.f, 0.f, 0.f, 0.f}, v1 = v0;
  if (j < counts[b]) {
    const float4* mr = (const float4*)(mx + ((size_t)b * L + src[row]) * D);
    v0 = mr[lane * 2];
    v1 = mr[lane * 2 + 1];
  }
  s16x8 o;
  o[0] = (short)f2bf(v0.x); o[1] = (short)f2bf(v0.y);
  o[2] = (short)f2bf(v0.z); o[3] = (short)f2bf(v0.w);
  o[4] = (short)f2bf(v1.x); o[5] = (short)f2bf(v1.y);
  o[6] = (short)f2bf(v1.z); o[7] = (short)f2bf(v1.w);
  *(s16x8*)(c + (size_t)row * D + lane * 8) = o;
}

// ---------------- 5b. weight transpose+convert ----------------
__global__ __launch_bounds__(256) void k_wt(const float* __restrict__ Wm,
                                            unsigned short* __restrict__ Wt, int N) {
  int idx = blockIdx.x * 256 + threadIdx.x;   // n*512 + k
  int n = idx >> 9, kk = idx & 511;
  Wt[idx] = f2bf(Wm[(size_t)kk * N + n]);
}

// ---------------- 6. bf16 MFMA GEMM + silu ----------------
__global__ __launch_bounds__(256) void k_gemm_mfma(const unsigned short* __restrict__ A,
                                                   const unsigned short* __restrict__ Bt,
                                                   float* __restrict__ outF,
                                                   unsigned short* __restrict__ outT,
                                                   int N, int mode) {
  __shared__ char As[16384];   // [128 rows][64 k] bf16, XOR-swizzled
  __shared__ char Bs[16384];
  int tid = threadIdx.x;
  int w = tid >> 6, l = tid & 63;
  int m0 = blockIdx.x * 128, n0 = blockIdx.y * 128;
  int wr = w >> 1, wc = w & 1;
  f32x4 acc[4][4];
  f32x4 zz = {0.f, 0.f, 0.f, 0.f};
#pragma unroll
  for (int mi = 0; mi < 4; ++mi)
#pragma unroll
    for (int ni = 0; ni < 4; ++ni) acc[mi][ni] = zz;

  for (int k0 = 0; k0 < 512; k0 += 64) {
#pragma unroll
    for (int ld = 0; ld < 4; ++ld) {
      int li = w * 4 + ld;
      int row = li * 8 + (l >> 3);
      int col = (((l & 7) ^ (row & 7)) << 3);
      gld16(A + (size_t)(m0 + row) * 512 + k0 + col, As + li * 1024);
      gld16(Bt + (size_t)(n0 + row) * 512 + k0 + col, Bs + li * 1024);
    }
    __syncthreads();
    s16x8 af[4][2], bfr[4][2];
#pragma unroll
    for (int kh = 0; kh < 2; ++kh) {
#pragma unroll
      for (int mi = 0; mi < 4; ++mi) {
        int row = wr * 64 + mi * 16 + (l & 15);
        int byte = row * 128 + ((kh * 64 + ((l >> 4) * 16)) ^ ((row & 7) << 4));
        af[mi][kh] = *(const s16x8*)(As + byte);
      }
#pragma unroll
      for (int ni = 0; ni < 4; ++ni) {
        int row = wc * 64 + ni * 16 + (l & 15);
        int byte = row * 128 + ((kh * 64 + ((l >> 4) * 16)) ^ ((row & 7) << 4));
        bfr[ni][kh] = *(const s16x8*)(Bs + byte);
      }
    }
#pragma unroll
    for (int kh = 0; kh < 2; ++kh)
#pragma unroll
      for (int mi = 0; mi < 4; ++mi)
#pragma unroll
        for (int ni = 0; ni < 4; ++ni)
          acc[mi][ni] = __builtin_amdgcn_mfma_f32_16x16x32_bf16(af[mi][kh], bfr[ni][kh], acc[mi][ni], 0, 0, 0);
    __syncthreads();
  }
#pragma unroll
  for (int mi = 0; mi < 4; ++mi)
#pragma unroll
    for (int ni = 0; ni < 4; ++ni)
#pragma unroll
      for (int r = 0; r < 4; ++r) {
        float vv = acc[mi][ni][r];
        vv = vv / (1.0f + __expf(-vv));     // silu
        int mrow = m0 + wr * 64 + mi * 16 + (l >> 4) * 4 + r;
        int ncol = n0 + wc * 64 + ni * 16 + (l & 15);
        if (mode == 0) {
          outF[(size_t)mrow * N + ncol] = vv;
        } else {
          int b = mrow >> 13, j = mrow & 8191;
          outT[((size_t)(b * 512 + ncol)) * 8192 + j] = f2bf(vv);
        }
      }
}

// ---------------- 7. rotary -> bf16 q/k ----------------
__global__ __launch_bounds__(256) void k_rot(const float* __restrict__ z,
                                             const float* __restrict__ qg,
                                             const float* __restrict__ qb,
                                             const float* __restrict__ kg,
                                             const float* __restrict__ kb,
                                             unsigned short* __restrict__ qo,
                                             unsigned short* __restrict__ ko) {
  int tid = blockIdx.x * 256 + threadIdx.x;
  int i = tid & 63;
  int row = tid >> 6;
  int j = row & (L - 1);
  double freq = exp(((double)(-2 * i) / 128.0) * log(10000.0));
  float angf = (float)j * (float)freq;
  double sa, ca;
  sincos((double)angf, &sa, &ca);
  float cc = (float)ca, ss = (float)sa;
  size_t base = (size_t)row * Z + 2 * i;
  float z1 = z[base], z2 = z[base + 1];
  float q1 = z1 * qg[2 * i] + qb[2 * i], q2 = z2 * qg[2 * i + 1] + qb[2 * i + 1];
  float k1 = z1 * kg[2 * i] + kb[2 * i], k2 = z2 * kg[2 * i + 1] + kb[2 * i + 1];
  qo[base]     = f2bf(q1 * cc - q2 * ss);
  qo[base + 1] = f2bf(q1 * ss + q2 * cc);
  ko[base]     = f2bf(k1 * cc - k2 * ss);
  ko[base + 1] = f2bf(k1 * ss + k2 * cc);
}

// ---------------- 8. MFMA windowed attention ----------------
__global__ __launch_bounds__(512) void k_attn_mfma(const unsigned short* __restrict__ q,
                                                   const unsigned short* __restrict__ k,
                                                   const unsigned short* __restrict__ vT,
                                                   const float* __restrict__ relb,
                                                   const int* __restrict__ counts,
                                                   float* __restrict__ h) {
  __shared__ char smem[131072];
  char* Qs = smem;
  char* Ks = smem + 32768;
  char* Ps = smem;
  char* Vs = smem + 65536;
  int tid = threadIdx.x, w = tid >> 6, l = tid & 63;
  int n = blockIdx.x & 63, b = blockIdx.x >> 6;
  int cnt = counts[b];
  int q0 = n * 128, kbase = q0 - 128;
  const size_t rowb = (size_t)b * L;

#pragma unroll
  for (int ld = 0; ld < 4; ++ld) {
    int li = w * 4 + ld;
    int row = li * 4 + (l >> 4);
    int colb = ((l & 15) * 16) ^ ((row & 7) << 4);
    gld16((const char*)(q + (rowb + q0 + row) * Z) + colb, Qs + li * 1024);
  }
#pragma unroll
  for (int ld = 0; ld < 8; ++ld) {
    int li = w * 8 + ld;
    int row = li * 4 + (l >> 4);
    int jk = kbase + row; if (jk < 0) jk = 0;
    int colb = ((l & 15) * 16) ^ ((row & 7) << 4);
    gld16((const char*)(k + (rowb + jk) * Z) + colb, Ks + li * 1024);
  }
  __syncthreads();

  int m0 = w * 16;
  f32x4 s[16];
  f32x4 zz = {0.f, 0.f, 0.f, 0.f};
#pragma unroll
  for (int ni = 0; ni < 16; ++ni) s[ni] = zz;
  s16x8 aq[4];
#pragma unroll
  for (int ks = 0; ks < 4; ++ks) {
    int row = m0 + (l & 15);
    int byte = row * 256 + ((ks * 64 + ((l >> 4) * 16)) ^ ((row & 7) << 4));
    aq[ks] = *(const s16x8*)(Qs + byte);
  }
#pragma unroll
  for (int ni = 0; ni < 16; ++ni) {
    int row = ni * 16 + (l & 15);
    int rb = row * 256, sw = (row & 7) << 4;
#pragma unroll
    for (int ks = 0; ks < 4; ++ks) {
      s16x8 bk = *(const s16x8*)(Ks + rb + ((ks * 64 + ((l >> 4) * 16)) ^ sw));
      s[ni] = __builtin_amdgcn_mfma_f32_16x16x32_bf16(aq[ks], bk, s[ni], 0, 0, 0);
    }
  }
  __syncthreads();

  auto stageV = [&](int nc) {
#pragma unroll
    for (int ld = 0; ld < 8; ++ld) {
      int li = w * 8 + ld;
      int row = li * 2 + (l >> 5);
      int colb = ((l & 31) * 16) ^ ((row & 7) << 4);
      int j = kbase + (colb >> 1);
      if (j < 0) j = 0;
      gld16((const char*)(vT + ((size_t)(b * 512 + nc * 128 + row)) * L + j), Vs + li * 1024);
    }
  };
  stageV(0);

  int rgrp = (l >> 4) * 4;
  float mxr[4] = {-3e38f, -3e38f, -3e38f, -3e38f};
#pragma unroll
  for (int ni = 0; ni < 16; ++ni) {
    int col = ni * 16 + (l & 15);
    int kabs = kbase + col;
#pragma unroll
    for (int r = 0; r < 4; ++r) {
      int ww = m0 + rgrp + r;
      bool valid = (kabs >= 0) && (kabs <= q0 + ww) && (kabs < cnt);
      float vv = valid ? (s[ni][r] * 0.08838834764831845f + relb[col + 127 - ww]) : NEGF;
      s[ni][r] = vv;
      mxr[r] = fmaxf(mxr[r], vv);
    }
  }
#pragma unroll
  for (int r = 0; r < 4; ++r)
    for (int off = 1; off < 16; off <<= 1)
      mxr[r] = fmaxf(mxr[r], __shfl_xor(mxr[r], off, 64));
  float smr[4] = {0.f, 0.f, 0.f, 0.f};
#pragma unroll
  for (int ni = 0; ni < 16; ++ni)
#pragma unroll
    for (int r = 0; r < 4; ++r) {
      float p = __expf(s[ni][r] - mxr[r]);
      s[ni][r] = p;
      smr[r] += p;
    }
#pragma unroll
  for (int r = 0; r < 4; ++r) {
    for (int off = 1; off < 16; off <<= 1) smr[r] += __shfl_xor(smr[r], off, 64);
    smr[r] = 1.0f / smr[r];
  }
#pragma unroll
  for (int ni = 0; ni < 16; ++ni) {
    int colb2 = (ni * 16 + (l & 15)) * 2;
#pragma unroll
    for (int r = 0; r < 4; ++r) {
      int row = m0 + rgrp + r;
      *(unsigned short*)(Ps + row * 512 + (colb2 ^ ((row & 7) << 4))) = f2bf(s[ni][r] * smr[r]);
    }
  }
  __syncthreads();

  for (int nc = 0; nc < 4; ++nc) {
    if (nc) {
      __syncthreads();
      stageV(nc);
      __syncthreads();
    }
    f32x4 o[8];
#pragma unroll
    for (int ni = 0; ni < 8; ++ni) o[ni] = zz;
    int prow = m0 + (l & 15);
    int psw = (prow & 7) << 4;
#pragma unroll
    for (int kt = 0; kt < 4; ++kt) {
      s16x8 pa0 = *(const s16x8*)(Ps + prow * 512 + ((kt * 128 + ((l >> 4) * 16)) ^ psw));
      s16x8 pa1 = *(const s16x8*)(Ps + prow * 512 + ((kt * 128 + 64 + ((l >> 4) * 16)) ^ psw));
#pragma unroll
      for (int ni = 0; ni < 8; ++ni) {
        int vrow = ni * 16 + (l & 15);
        int vsw = (vrow & 7) << 4;
        s16x8 vb0 = *(const s16x8*)(Vs + vrow * 512 + ((kt * 128 + ((l >> 4) * 16)) ^ vsw));
        s16x8 vb1 = *(const s16x8*)(Vs + vrow * 512 + ((kt * 128 + 64 + ((l >> 4) * 16)) ^ vsw));
        o[ni] = __builtin_amdgcn_mfma_f32_16x16x32_bf16(pa0, vb0, o[ni], 0, 0, 0);
        o[ni] = __builtin_amdgcn_mfma_f32_16x16x32_bf16(pa1, vb1, o[ni], 0, 0, 0);
      }
    }
#pragma unroll
    for (int ni = 0; ni < 8; ++ni)
#pragma unroll
      for (int r = 0; r < 4; ++r)
        h[(rowb + q0 + m0 + rgrp + r) * 512 + nc * 128 + ni * 16 + (l & 15)] = o[ni][r];
  }
}

// ---------------- 9. out = x + gather(h, idx) * pi  (float4) ----------------
__global__ __launch_bounds__(256) void k_final(const float* __restrict__ x,
                                               const float* __restrict__ h,
                                               const float* __restrict__ pi,
                                               const int* __restrict__ idx,
                                               float* __restrict__ out) {
  int e4 = blockIdx.x * 256 + threadIdx.x;     // float4 index
  int dq = e4 & 127;
  int rem = e4 >> 7;                            // l*B + b
  int b = rem & 3;
  int l = rem >> 2;
  float4 xv = ((const float4*)x)[e4];
  int ix = idx[(b << 13) + l];
  if (ix > 0) {
    float pv = pi[(b << 13) + l];
    float4 hv = ((const float4*)(h + ((size_t)(b << 13) + ix - 1) * 512))[dq];
    xv.x += hv.x * pv; xv.y += hv.y * pv;
    xv.z += hv.z * pv; xv.w += hv.w * pv;
  }
  ((float4*)out)[e4] = xv;
}

extern "C" void kernel_launch(void* const* d_in, const int* in_sizes, int n_in,
                              void* d_out, int out_size, void* d_ws, size_t ws_size,
                              hipStream_t stream) {
  const float* x     = (const float*)d_in[0];
  const float* delta = (const float*)d_in[1];
  const float* alpha = (const float*)d_in[2];
  const float* beta  = (const float*)d_in[3];
  const float* gamma = (const float*)d_in[4];
  const float* omega = (const float*)d_in[5];
  const float* Wp    = (const float*)d_in[6];
  const float* bp    = (const float*)d_in[7];
  const float* temp  = (const float*)d_in[8];
  const float* Wz    = (const float*)d_in[9];
  const float* qg    = (const float*)d_in[10];
  const float* qb    = (const float*)d_in[11];
  const float* kg    = (const float*)d_in[12];
  const float* kb    = (const float*)d_in[13];
  const float* Wv    = (const float*)d_in[14];
  const float* relb  = (const float*)d_in[15];
  (void)in_sizes; (void)n_in; (void)out_size; (void)ws_size;

  char* wsb = (char*)d_ws;
  size_t o = 0;
  auto alloc = [&](size_t bytes) {
    char* p = wsb + o;
    o += (bytes + 255) & ~(size_t)255;
    return p;
  };
  float* mxv           = (float*)alloc((size_t)B * L * D * 4);          // mx, reused as h
  // E (16.8 MB fp32, dead after k_convC) aliases with cb (32 MB, written after)
  char*  eAndCb        = alloc((size_t)B * L * D * 2);
  float* Ebuf          = (float*)eAndCb;                                // B*NCH*NDIM*512*4 = 16.8 MB
  unsigned short* cb   = (unsigned short*)eAndCb;                       // c bf16
  float* zb            = (float*)alloc((size_t)B * L * Z * 4);
  unsigned short* qb2  = (unsigned short*)alloc((size_t)B * L * Z * 2);
  unsigned short* kb2  = (unsigned short*)alloc((size_t)B * L * Z * 2);
  unsigned short* vTb  = (unsigned short*)alloc((size_t)B * D * L * 2); // v^T [B][D][L]
  unsigned short* wzt  = (unsigned short*)alloc((size_t)Z * 512 * 2);
  unsigned short* wvt  = (unsigned short*)alloc((size_t)D * 512 * 2);
  float* pib = (float*)alloc((size_t)B * L * 4);
  int* selb  = (int*)alloc((size_t)B * L * 4);
  int* idx   = (int*)alloc((size_t)B * L * 4);
  int* src   = (int*)alloc((size_t)B * L * 4);
  int* cnt   = (int*)alloc(256);
  double* qdn = (double*)alloc((size_t)D * NDIM * 8);
  double* cdn = (double*)alloc((size_t)D * NDIM * 8);
  double* rp1 = (double*)alloc((size_t)D * NDIM * 8);
  double* rp2 = (double*)alloc((size_t)D * NDIM * 8);

  k_prep<<<(D * NDIM + 255) / 256, 256, 0, stream>>>(delta, alpha, beta, gamma, qdn, cdn, rp1, rp2);
  k_convA<<<B * 8 * 32, 256, 0, stream>>>(x, qdn, Ebuf);
  k_convC<<<B * 8 * 32, 256, 0, stream>>>(x, omega, qdn, cdn, rp1, rp2, Ebuf, mxv);
  k_logit<<<B * L / 4, 256, 0, stream>>>(mxv, Wp, bp, temp, pib, selb);
  k_scan<<<B, 256, 0, stream>>>(selb, idx, src, cnt);
  k_buildc<<<B * L / 4, 256, 0, stream>>>(mxv, src, cnt, cb);
  k_wt<<<Z * 512 / 256, 256, 0, stream>>>(Wz, wzt, Z);
  k_wt<<<D * 512 / 256, 256, 0, stream>>>(Wv, wvt, D);
  k_gemm_mfma<<<dim3(256, 1), 256, 0, stream>>>(cb, wzt, zb, vTb, Z, 0);
  k_gemm_mfma<<<dim3(256, 4), 256, 0, stream>>>(cb, wvt, zb, vTb, D, 1);
  k_rot<<<B * L * (Z / 2) / 256, 256, 0, stream>>>(zb, qg, qb, kg, kb, qb2, kb2);
  k_attn_mfma<<<B * 64, 512, 0, stream>>>(qb2, kb2, vTb, relb, cnt, mxv);
  k_final<<<(int)((size_t)L * B * D / 4 / 256), 256, 0, stream>>>(x, mxv, pib, idx, (float*)d_out);
}